// Round 6
// baseline (26.572 us; speedup 1.0000x reference)
//
#include <hip/hip_runtime.h>

// NSLayer: out = X + (-a*(X X^T) + b*(X X^T)^2) X per (b,c) slice, X: [512][64].
// Factored: G = X^T X (64x64), H = -a*G + b*G^2 (symmetric), out = X + X*H.
// bf16 MFMA (32x32x16), fp32 accumulate. 512 blocks x 512 threads (8 waves).
// Round 6: latency-pipelined streaming —
//   * prefetch-1 chunk ping-pong: pass-1 MFMA tracks the HBM load stream
//     instead of waiting for the full 128 KiB block load (was ~10 us exposed)
//   * chunk->half remap (chunk = 2s+half): pass-3 staging balanced across halves
//   * pass-3 tile 0 staged into Xr during the G-reduce/pass-2 bubble

typedef __bf16 bf16;
typedef __attribute__((ext_vector_type(8)))  __bf16 bf16x8;
typedef __attribute__((ext_vector_type(4)))  __bf16 bf16x4;
typedef __attribute__((ext_vector_type(16))) float  f32x16;

namespace {

__device__ __forceinline__ int sxz(int d) { return ((d >> 1) ^ (d >> 4)) & 7; }

__global__ __launch_bounds__(512, 4)
void ns_mfma(const float* __restrict__ inp, const float* __restrict__ aw,
             const float* __restrict__ bw, float* __restrict__ out) {
    // LDS map (54272 B):
    //   [0,18432):      pass1: Xt0[64][72]bf16 + Xt1[64][72]bf16
    //                   pass3: Xr[128][72]bf16 (overlay)
    //   [18432,35840):  Gp[64][68]f32 partial (half-0's G)
    //   [35840,45056):  Gbf[64][72]bf16
    //   [45056,54272):  Hbf[64][72]bf16
    __shared__ unsigned char smem[54272] __attribute__((aligned(128)));
    bf16*  const Xt0 = (bf16*)smem;
    bf16*  const Xt1 = (bf16*)(smem + 9216);
    bf16*  const Xr  = (bf16*)smem;
    float* const Gp  = (float*)(smem + 18432);
    bf16*  const Gbf = (bf16*)(smem + 35840);
    bf16*  const Hbf = (bf16*)(smem + 45056);

    const int slice = blockIdx.x;                // b*64 + c
    const float* __restrict__ X = inp + (size_t)slice * (512 * 64);
    float* __restrict__ O       = out + (size_t)slice * (512 * 64);

    const int t    = threadIdx.x;
    const int lane = t & 63;
    const int w    = t >> 6;       // wave 0..7
    const int l31  = lane & 31;
    const int l5   = lane >> 5;    // 0/1
    const int half = t >> 8;       // == w>>2
    const int th   = t & 255;
    const int s_nq = th >> 4;      // 0..15
    const int s_dq = th & 15;      // 0..15

    // Thread in half h owns chunks (2s+h), s=0..3: rows 64*(2s+h)+4*s_nq+rn.
    const float* __restrict__ Xbase =
        X + (size_t)(64 * half + 4 * s_nq) * 64 + 4 * s_dq;

    // issue chunk-0 loads immediately
    float4 rv[2][4];
#pragma unroll
    for (int rn = 0; rn < 4; ++rn)
        rv[0][rn] = *(const float4*)&Xbase[(size_t)rn * 64];

    const float av = aw[slice & 63];
    const float bv = bw[slice & 63];

    // ================= Pass 1: G = X^T X, K-split across halves ============
    f32x16 acc;
#pragma unroll
    for (int q = 0; q < 16; ++q) acc[q] = 0.f;

    bf16* const XtMine = half ? Xt1 : Xt0;
    const int tile = w & 3;
    const int i32  = (tile >> 1) * 32;
    const int j32  = (tile & 1) * 32;
    const int rowA = i32 + l31;
    const int rowB = j32 + l31;
    const int sA   = sxz(rowA);
    const int sB   = sxz(rowB);

    bf16x4 xr[4][4];   // retained bf16 copy of this thread's X share

#pragma unroll
    for (int it = 0; it < 4; ++it) {
        // prefetch next chunk (issue before touching current data)
        if (it < 3) {
#pragma unroll
            for (int rn = 0; rn < 4; ++rn)
                rv[(it + 1) & 1][rn] =
                    *(const float4*)&Xbase[(size_t)(128 * (it + 1) + rn) * 64];
        }
        // convert current chunk -> xr[it]
#pragma unroll
        for (int rn = 0; rn < 4; ++rn) {
            const float4 v = rv[it & 1][rn];
            xr[it][rn][0] = (bf16)v.x; xr[it][rn][1] = (bf16)v.y;
            xr[it][rn][2] = (bf16)v.z; xr[it][rn][3] = (bf16)v.w;
        }
        // stage transposed into XtMine (16B-granule swizzle)
#pragma unroll
        for (int r = 0; r < 4; ++r) {
            const int d = 4 * s_dq + r;
            bf16x4 v;
            v[0] = xr[it][0][r]; v[1] = xr[it][1][r];
            v[2] = xr[it][2][r]; v[3] = xr[it][3][r];
            const int g = ((s_nq >> 1) ^ sxz(d)) & 7;
            *(bf16x4*)&XtMine[d * 72 + g * 8 + 4 * (s_nq & 1)] = v;
        }
        __syncthreads();
        // 4 K-steps (K=16 each) over this 64-n chunk
#pragma unroll
        for (int ks = 0; ks < 4; ++ks) {
            const int gw = 2 * ks + l5;
            bf16x8 a = *(const bf16x8*)&XtMine[rowA * 72 + ((gw ^ sA) & 7) * 8];
            bf16x8 b = *(const bf16x8*)&XtMine[rowB * 72 + ((gw ^ sB) & 7) * 8];
            acc = __builtin_amdgcn_mfma_f32_32x32x16_bf16(a, b, acc, 0, 0, 0);
        }
        __syncthreads();
    }

    // ====== G reduce (sequential) + early-stage pass-3 tile 0 ==============
    if (half == 0) {
#pragma unroll
        for (int q = 0; q < 16; ++q) {
            const int r = (q & 3) + 8 * (q >> 2) + 4 * l5;   // C/D row (m74/m101)
            Gp[(i32 + r) * 68 + j32 + l31] = acc[q];
        }
    }
    // Xt dead after pass-1's final barrier: stage rows 0..127 (chunks 0,1)
#pragma unroll
    for (int rn = 0; rn < 4; ++rn)
        *(bf16x4*)&Xr[(64 * half + 4 * s_nq + rn) * 72 + 4 * s_dq] = xr[0][rn];
    __syncthreads();
    if (half == 1) {
#pragma unroll
        for (int q = 0; q < 16; ++q) {
            const int r  = (q & 3) + 8 * (q >> 2) + 4 * l5;
            const int ii = i32 + r;
            const int jj = j32 + l31;
            Gbf[ii * 72 + jj] = (bf16)(acc[q] + Gp[ii * 68 + jj]);
        }
    }
    __syncthreads();

    // ================= Pass 2: H = b*G^2 - a*G (waves 0-3) =================
    if (w < 4) {
        const int pi = (w >> 1) * 32;
        const int pj = (w & 1) * 32;
        f32x16 h;
#pragma unroll
        for (int q = 0; q < 16; ++q) h[q] = 0.f;
#pragma unroll
        for (int ks = 0; ks < 4; ++ks) {
            // G symmetric: both operands are row reads of Gbf
            bf16x8 a = *(const bf16x8*)&Gbf[(pi + l31) * 72 + ks * 16 + 8 * l5];
            bf16x8 b = *(const bf16x8*)&Gbf[(pj + l31) * 72 + ks * 16 + 8 * l5];
            h = __builtin_amdgcn_mfma_f32_32x32x16_bf16(a, b, h, 0, 0, 0);
        }
#pragma unroll
        for (int q = 0; q < 16; ++q) {
            const int r  = (q & 3) + 8 * (q >> 2) + 4 * l5;
            const int ii = pi + r;
            const int jj = pj + l31;
            Hbf[ii * 72 + jj] = (bf16)(bv * h[q] - av * (float)Gbf[ii * 72 + jj]);
        }
    }
    __syncthreads();

    // ================= Pass 3: out = X + X*H (Xr pre-staged for it=0) ======
    const int nb = (w >> 1) * 32;   // n-block within 128-row tile
    const int db = (w & 1) * 32;    // d-block

#pragma unroll
    for (int it = 0; it < 4; ++it) {
        f32x16 o;
#pragma unroll
        for (int q = 0; q < 16; ++q) o[q] = 0.f;
#pragma unroll
        for (int ks = 0; ks < 4; ++ks) {
            bf16x8 a = *(const bf16x8*)&Xr [(nb + l31) * 72 + ks * 16 + 8 * l5];
            bf16x8 b = *(const bf16x8*)&Hbf[(db + l31) * 72 + ks * 16 + 8 * l5];
            o = __builtin_amdgcn_mfma_f32_32x32x16_bf16(a, b, o, 0, 0, 0);
        }
        // epilogue: out = X + X*H; 128B-contiguous dword stores
#pragma unroll
        for (int q = 0; q < 16; ++q) {
            const int rl = (q & 3) + 8 * (q >> 2) + 4 * l5;
            const int nl = nb + rl;
            const int d  = db + l31;
            O[(size_t)(it * 128 + nl) * 64 + d] = o[q] + (float)Xr[nl * 72 + d];
        }
        if (it < 3) {
            __syncthreads();   // all Xr reads of tile it done
#pragma unroll
            for (int rn = 0; rn < 4; ++rn)
                *(bf16x4*)&Xr[(64 * half + 4 * s_nq + rn) * 72 + 4 * s_dq] = xr[it + 1][rn];
            __syncthreads();   // tile it+1 staged
        }
    }
}

}  // namespace

extern "C" void kernel_launch(void* const* d_in, const int* in_sizes, int n_in,
                              void* d_out, int out_size, void* d_ws, size_t ws_size,
                              hipStream_t stream) {
    const float* inp = (const float*)d_in[0];
    const float* aw  = (const float*)d_in[1];
    const float* bw  = (const float*)d_in[2];
    float* out       = (float*)d_out;

    ns_mfma<<<dim3(512), dim3(512), 0, stream>>>(inp, aw, bw, out);
}